// Round 3
// baseline (415.739 us; speedup 1.0000x reference)
//
#include <hip/hip_runtime.h>

#define NN 4096
#define CAP 384          // nnz/row: mean 205, sd 13.9 -> 384 is +12.9 sd; dense fallback guards
#define SLOPE 0.2f

// ---- workspace layout (float offsets unless noted) ----
#define V_OFF     0                        // v1i,v2i,v1s,v2s : 4*128
#define C_OFF     512                      // 4 score constants
#define BT_OFF    516                      // b_total[128]
#define S_OFF     1024                     // s1i,s2i,s1s,s2s : 4*4096
#define HXI_OFF   32768                    // Ld@x   [4096,128]
#define HXS_OFF   (HXI_OFF + NN*128)       // Lu@x
#define UI_OFF    (HXS_OFF + NN*128)       // x@Wi0 + Hxi@Wi1
#define US_OFF    (UI_OFF + NN*128)        // x@Ws0 + Hxs@Ws1
#define XWH_OFF   (US_OFF + NN*128)        // x@Wh
#define OI_OFF    (XWH_OFF + NN*128)       // alpha_irr @ U_irr
#define OS_OFF    (OI_OFF + NN*128)        // alpha_sol @ U_sol
#define ZP_OFF    (OS_OFF + NN*128)        // P@xWh split-K partials: 8 * [4096,128]
#define WS_FLOATS (ZP_OFF + 8*NN*128)
#define IDX_BYTE_OFF ((size_t)WS_FLOATS * 4)                  // u16 idx lists 2*4096*CAP
#define VAL_BYTE_OFF (IDX_BYTE_OFF + (size_t)2*NN*CAP*2)      // f32 val lists
#define CNT_BYTE_OFF (VAL_BYTE_OFF + (size_t)2*NN*CAP*4)      // int counts 2*4096
// total ws ≈ 50.5 MiB

// ---------------------------------------------------------------------------
// Prep: v-vectors so s1[i] = x[i,:]·v + c (x_irr never materialized), b_total.
__global__ __launch_bounds__(128) void k_prep(
    const float* __restrict__ Wi_w, const float* __restrict__ Wi_b,
    const float* __restrict__ Ws_w, const float* __restrict__ Ws_b,
    const float* __restrict__ Wh_b, const float* __restrict__ att_irr,
    const float* __restrict__ att_sol, float* __restrict__ ws) {
  const int t = threadIdx.x;  // one thread per input channel c
  float v1i = 0.f, v2i = 0.f, v1s = 0.f, v2s = 0.f;
  for (int j = 0; j < 2; ++j) {
    for (int o = 0; o < 128; ++o) {
      const float wi = Wi_w[j*16384 + t*128 + o];
      const float wv = Ws_w[j*16384 + t*128 + o];
      v1i += wi * att_irr[j*128 + o];
      v2i += wi * att_irr[256 + j*128 + o];
      v1s += wv * att_sol[j*128 + o];
      v2s += wv * att_sol[256 + j*128 + o];
    }
  }
  ws[V_OFF + t]       = v1i;
  ws[V_OFF + 128 + t] = v2i;
  ws[V_OFF + 256 + t] = v1s;
  ws[V_OFF + 384 + t] = v2s;
  ws[BT_OFF + t] = Wi_b[t] + Wi_b[128 + t] + Ws_b[t] + Ws_b[128 + t] + Wh_b[t];
  if (t < 4) {
    const float* bb = (t < 2) ? Wi_b : Ws_b;
    const float* aa = ((t < 2) ? att_irr : att_sol) + ((t & 1) ? 256 : 0);
    float c = 0.f;
    for (int k = 0; k < 256; ++k) c += bb[k] * aa[k];
    ws[C_OFF + t] = c;   // c1i, c2i, c1s, c2s
  }
}

// ---------------------------------------------------------------------------
__global__ __launch_bounds__(256) void k_scores(const float* __restrict__ x,
                                                float* __restrict__ ws) {
  const int wave = threadIdx.x >> 6, lane = threadIdx.x & 63;
  const int row = blockIdx.x * 4 + wave;
  const float* v = ws + V_OFF;
  const float x0 = x[row*128 + lane];
  const float x1 = x[row*128 + 64 + lane];
  float p0 = x0 * v[lane]       + x1 * v[64 + lane];
  float p1 = x0 * v[128 + lane] + x1 * v[192 + lane];
  float p2 = x0 * v[256 + lane] + x1 * v[320 + lane];
  float p3 = x0 * v[384 + lane] + x1 * v[448 + lane];
  #pragma unroll
  for (int off = 32; off; off >>= 1) {
    p0 += __shfl_down(p0, off);
    p1 += __shfl_down(p1, off);
    p2 += __shfl_down(p2, off);
    p3 += __shfl_down(p3, off);
  }
  if (lane == 0) {
    ws[S_OFF + row]          = p0 + ws[C_OFF + 0];  // s1_irr
    ws[S_OFF + NN + row]     = p1 + ws[C_OFF + 1];  // s2_irr
    ws[S_OFF + 2*NN + row]   = p2 + ws[C_OFF + 2];  // s1_sol
    ws[S_OFF + 3*NN + row]   = p3 + ws[C_OFF + 3];  // s2_sol
  }
}

// ---------------------------------------------------------------------------
__global__ __launch_bounds__(256) void k_zero(int* __restrict__ cnt) {
  cnt[blockIdx.x * 256 + threadIdx.x] = 0;   // grid 32 -> 8192 counters
}

// ---------------------------------------------------------------------------
// CSR build: one wave per quarter-row (1024 elements). 16 independent ballots,
// ONE global atomic per wave, scatter-store (idx u16, val f32). No LDS, no
// barriers. HBM-bound coalesced scan of Lu+Ld (128 MB).
__global__ __launch_bounds__(256) void k_csr(
    const float* __restrict__ Ld, const float* __restrict__ Lu,
    int* __restrict__ cntbuf, unsigned short* __restrict__ idxb,
    float* __restrict__ valb) {
  const int w = threadIdx.x >> 6, lane = threadIdx.x & 63;
  const int W = blockIdx.x * 4 + w;          // 0..32767
  const int br = W >> 14;                    // 16384 quarter-chunks per matrix
  const int row = (W >> 2) & (NN - 1);
  const int quarter = W & 3;
  const float4* __restrict__ L4 =
      (const float4*)((br ? Lu : Ld) + (size_t)row * NN + quarter * 1024);
  float4 lv[4];
  #pragma unroll
  for (int i = 0; i < 4; ++i) lv[i] = L4[i*64 + lane];

  unsigned long long m[16];
  int runs[16];
  int run = 0;
  #pragma unroll
  for (int i = 0; i < 4; ++i)
    #pragma unroll
    for (int c = 0; c < 4; ++c) {
      const int r = i*4 + c;
      m[r] = __ballot((&lv[i].x)[c] != 0.f);
      runs[r] = run;
      run += (int)__popcll(m[r]);
    }
  int base = 0;
  if (lane == 0 && run) base = atomicAdd(&cntbuf[br*NN + row], run);
  base = __shfl(base, 0);
  const size_t rb = (size_t)(br*NN + row) * CAP;
  const unsigned long long lmask = (1ull << lane) - 1ull;
  #pragma unroll
  for (int i = 0; i < 4; ++i)
    #pragma unroll
    for (int c = 0; c < 4; ++c) {
      const int r = i*4 + c;
      const float v = (&lv[i].x)[c];
      if (v != 0.f) {
        const int pos = base + runs[r] + (int)__popcll(m[r] & lmask);
        if (pos < CAP) {
          idxb[rb + pos] = (unsigned short)(quarter*1024 + (i*64 + lane)*4 + c);
          valb[rb + pos] = v;
        }
      }
    }
}

// ---------------------------------------------------------------------------
// Hx = L@x per row. ONE WAVE PER ROW, no LDS, no barriers. Pass 1: list
// metadata into 6 regs/lane. Pass 2: shfl-broadcast, 8 gathers in flight.
__global__ __launch_bounds__(256) void k_gather_hx(
    const float* __restrict__ Ld, const float* __restrict__ Lu,
    const float* __restrict__ x, float* __restrict__ ws,
    const unsigned short* __restrict__ idxb, const float* __restrict__ valb,
    const int* __restrict__ cntbuf) {
  const int w = threadIdx.x >> 6, lane = threadIdx.x & 63;
  const int W = blockIdx.x * 4 + w;       // 0..8191
  const int br = W >> 12;
  const int row = W & (NN - 1);
  const float2* __restrict__ x2 = (const float2*)x;
  float2* __restrict__ Hx2 = (float2*)(ws + (br ? HXS_OFF : HXI_OFF));
  const int cnt = cntbuf[br*NN + row];
  float a0 = 0.f, a1 = 0.f;
  if (cnt <= CAP) {
    const size_t rb = (size_t)(br*NN + row) * CAP;
    int jv[6]; float vv[6];
    #pragma unroll
    for (int s = 0; s < 6; ++s) {
      const int p = s*64 + lane;
      const bool in = p < cnt;
      jv[s] = in ? (int)idxb[rb + p] : 0;
      vv[s] = in ? valb[rb + p] : 0.f;
    }
    #pragma unroll
    for (int s = 0; s < 6; ++s) {
      if (s*64 < cnt) {
        const int qn = min(64, cnt - s*64);
        const int jvs = jv[s]; const float vvs = vv[s];
        int q = 0;
        for (; q + 8 <= qn; q += 8) {
          const int j0=__shfl(jvs,q+0), j1=__shfl(jvs,q+1), j2=__shfl(jvs,q+2), j3=__shfl(jvs,q+3);
          const int j4=__shfl(jvs,q+4), j5=__shfl(jvs,q+5), j6=__shfl(jvs,q+6), j7=__shfl(jvs,q+7);
          const float v0=__shfl(vvs,q+0), v1=__shfl(vvs,q+1), v2=__shfl(vvs,q+2), v3=__shfl(vvs,q+3);
          const float v4=__shfl(vvs,q+4), v5=__shfl(vvs,q+5), v6=__shfl(vvs,q+6), v7=__shfl(vvs,q+7);
          const float2 g0=x2[j0*64+lane], g1=x2[j1*64+lane], g2=x2[j2*64+lane], g3=x2[j3*64+lane];
          const float2 g4=x2[j4*64+lane], g5=x2[j5*64+lane], g6=x2[j6*64+lane], g7=x2[j7*64+lane];
          a0+=v0*g0.x; a1+=v0*g0.y; a0+=v1*g1.x; a1+=v1*g1.y;
          a0+=v2*g2.x; a1+=v2*g2.y; a0+=v3*g3.x; a1+=v3*g3.y;
          a0+=v4*g4.x; a1+=v4*g4.y; a0+=v5*g5.x; a1+=v5*g5.y;
          a0+=v6*g6.x; a1+=v6*g6.y; a0+=v7*g7.x; a1+=v7*g7.y;
        }
        for (; q < qn; ++q) {
          const int j = __shfl(jvs, q); const float v = __shfl(vvs, q);
          const float2 g = x2[j*64+lane];
          a0 += v*g.x; a1 += v*g.y;
        }
      }
    }
  } else {   // overflow fallback: dense rescan (never taken at 5% density)
    const float* __restrict__ Lrow = (br ? Lu : Ld) + (size_t)row * NN;
    for (int j = 0; j < NN; ++j) {
      const float v = Lrow[j];
      if (v != 0.f) { const float2 g = x2[j*64+lane]; a0 += v*g.x; a1 += v*g.y; }
    }
  }
  float2 o; o.x = a0; o.y = a1;
  Hx2[row*64 + lane] = o;
}

// ---------------------------------------------------------------------------
// Small GEMMs: U_irr = x@Wi0 + Hxi@Wi1 ; U_sol = x@Ws0 + Hxs@Ws1 ; xWh = x@Wh.
__global__ __launch_bounds__(256) void k_ugemm(
    const float* __restrict__ x, const float* __restrict__ Wi_w,
    const float* __restrict__ Ws_w, const float* __restrict__ Wh_w,
    float* __restrict__ ws) {
  const int rb = blockIdx.x;       // 128 row-blocks of 32
  const int sel = blockIdx.y;      // 0:U_irr 1:U_sol 2:xWh
  const float* A[2]; const float* W[2]; int npass; float* out;
  if (sel == 0)      { A[0]=x; W[0]=Wi_w; A[1]=ws+HXI_OFF; W[1]=Wi_w+16384; npass=2; out=ws+UI_OFF; }
  else if (sel == 1) { A[0]=x; W[0]=Ws_w; A[1]=ws+HXS_OFF; W[1]=Ws_w+16384; npass=2; out=ws+US_OFF; }
  else               { A[0]=x; W[0]=Wh_w; A[1]=nullptr;    W[1]=nullptr;    npass=1; out=ws+XWH_OFF; }

  __shared__ __align__(16) float At[32][33];
  __shared__ __align__(16) float Wt[32][132];
  const int t = threadIdx.x;
  const int rg = t >> 4, cg = t & 15;
  const int r0 = rb * 32;
  float acc[2][8];
  #pragma unroll
  for (int i = 0; i < 2; ++i)
    #pragma unroll
    for (int j = 0; j < 8; ++j) acc[i][j] = 0.f;

  for (int ps = 0; ps < npass; ++ps) {
    const float* __restrict__ Ap = A[ps];
    const float* __restrict__ Wp = W[ps];
    for (int k0 = 0; k0 < 128; k0 += 32) {
      __syncthreads();
      { const int row = t >> 3, kq = t & 7;
        const float4 av = *(const float4*)&Ap[(r0 + row)*128 + k0 + kq*4];
        At[row][kq*4+0] = av.x; At[row][kq*4+1] = av.y;
        At[row][kq*4+2] = av.z; At[row][kq*4+3] = av.w; }
      #pragma unroll
      for (int l = 0; l < 4; ++l) {
        const int idx = t + l*256;
        const int kr = idx >> 5, c4 = idx & 31;
        const float4 wv = *(const float4*)&Wp[(k0 + kr)*128 + c4*4];
        Wt[kr][c4*4+0] = wv.x; Wt[kr][c4*4+1] = wv.y;
        Wt[kr][c4*4+2] = wv.z; Wt[kr][c4*4+3] = wv.w;
      }
      __syncthreads();
      #pragma unroll
      for (int k = 0; k < 32; ++k) {
        const float a0 = At[rg*2 + 0][k];
        const float a1 = At[rg*2 + 1][k];
        const float4 b0 = *(const float4*)&Wt[k][cg*8];
        const float4 b1 = *(const float4*)&Wt[k][cg*8 + 4];
        acc[0][0] += a0*b0.x; acc[0][1] += a0*b0.y; acc[0][2] += a0*b0.z; acc[0][3] += a0*b0.w;
        acc[0][4] += a0*b1.x; acc[0][5] += a0*b1.y; acc[0][6] += a0*b1.z; acc[0][7] += a0*b1.w;
        acc[1][0] += a1*b0.x; acc[1][1] += a1*b0.y; acc[1][2] += a1*b0.z; acc[1][3] += a1*b0.w;
        acc[1][4] += a1*b1.x; acc[1][5] += a1*b1.y; acc[1][6] += a1*b1.z; acc[1][7] += a1*b1.w;
      }
    }
  }
  #pragma unroll
  for (int i = 0; i < 2; ++i) {
    const int r = r0 + rg*2 + i;
    #pragma unroll
    for (int j = 0; j < 8; ++j) out[r*128 + cg*8 + j] = acc[i][j];
  }
}

// ---------------------------------------------------------------------------
// Dense P @ xWh, split-K=8. P-tile stored TRANSPOSED in LDS (At[k][row], pad
// 68) so per-k A-reads are one ds_read_b128 instead of 4 scalar reads.
__global__ __launch_bounds__(256) void k_pgemm(const float* __restrict__ P,
                                               const float* __restrict__ ws,
                                               float* __restrict__ zpart) {
  const int rbl = blockIdx.x;   // 64 row-blocks of 64
  const int kz  = blockIdx.y;   // 8 K-splits of 512
  const float* __restrict__ Xw = ws + XWH_OFF;

  __shared__ __align__(16) float At[32][68];    // [k][row]
  __shared__ __align__(16) float Xt[32][132];
  const int t = threadIdx.x;
  const int rg = t >> 4, cg = t & 15;   // 16 x 4 rows, 16 x 8 cols
  const int r0 = rbl * 64;
  const int kbase = kz * 512;
  float acc[4][8];
  #pragma unroll
  for (int i = 0; i < 4; ++i)
    #pragma unroll
    for (int j = 0; j < 8; ++j) acc[i][j] = 0.f;

  for (int k0 = kbase; k0 < kbase + 512; k0 += 32) {
    __syncthreads();
    #pragma unroll
    for (int l = 0; l < 2; ++l) { // stage P: 64x32, transposed into LDS
      const int idx = t + l*256;
      const int row = idx >> 3, kq = idx & 7;
      const float4 pv = *(const float4*)&P[(size_t)(r0 + row)*NN + k0 + kq*4];
      At[kq*4+0][row] = pv.x; At[kq*4+1][row] = pv.y;
      At[kq*4+2][row] = pv.z; At[kq*4+3][row] = pv.w;
    }
    #pragma unroll
    for (int l = 0; l < 4; ++l) { // stage xWh: 32x128
      const int idx = t + l*256;
      const int kr = idx >> 5, c4 = idx & 31;
      const float4 xv = *(const float4*)&Xw[(k0 + kr)*128 + c4*4];
      Xt[kr][c4*4+0] = xv.x; Xt[kr][c4*4+1] = xv.y;
      Xt[kr][c4*4+2] = xv.z; Xt[kr][c4*4+3] = xv.w;
    }
    __syncthreads();
    #pragma unroll
    for (int k = 0; k < 32; ++k) {
      const float4 a  = *(const float4*)&At[k][rg*4];
      const float4 b0 = *(const float4*)&Xt[k][cg*8];
      const float4 b1 = *(const float4*)&Xt[k][cg*8 + 4];
      acc[0][0] += a.x*b0.x; acc[0][1] += a.x*b0.y; acc[0][2] += a.x*b0.z; acc[0][3] += a.x*b0.w;
      acc[0][4] += a.x*b1.x; acc[0][5] += a.x*b1.y; acc[0][6] += a.x*b1.z; acc[0][7] += a.x*b1.w;
      acc[1][0] += a.y*b0.x; acc[1][1] += a.y*b0.y; acc[1][2] += a.y*b0.z; acc[1][3] += a.y*b0.w;
      acc[1][4] += a.y*b1.x; acc[1][5] += a.y*b1.y; acc[1][6] += a.y*b1.z; acc[1][7] += a.y*b1.w;
      acc[2][0] += a.z*b0.x; acc[2][1] += a.z*b0.y; acc[2][2] += a.z*b0.z; acc[2][3] += a.z*b0.w;
      acc[2][4] += a.z*b1.x; acc[2][5] += a.z*b1.y; acc[2][6] += a.z*b1.z; acc[2][7] += a.z*b1.w;
      acc[3][0] += a.w*b0.x; acc[3][1] += a.w*b0.y; acc[3][2] += a.w*b0.z; acc[3][3] += a.w*b0.w;
      acc[3][4] += a.w*b1.x; acc[3][5] += a.w*b1.y; acc[3][6] += a.w*b1.z; acc[3][7] += a.w*b1.w;
    }
  }
  float* __restrict__ zp = zpart + (size_t)kz * NN * 128;
  #pragma unroll
  for (int i = 0; i < 4; ++i) {
    const int r = r0 + rg*4 + i;
    #pragma unroll
    for (int j = 0; j < 8; ++j) zp[r*128 + cg*8 + j] = acc[i][j];
  }
}

// ---------------------------------------------------------------------------
// Attention: one wave per (row,branch), no LDS/barriers. Pass 1: e_j into regs
// + wave-reduced denominator. Pass 2: shfl-broadcast, 8 U-gathers in flight.
// Masked entries underflow to exactly 0 in the reference -> skipping is exact.
__global__ __launch_bounds__(256) void k_attn(
    const float* __restrict__ Ld, const float* __restrict__ Lu,
    float* __restrict__ ws, const unsigned short* __restrict__ idxb,
    const int* __restrict__ cntbuf) {
  const int w = threadIdx.x >> 6, lane = threadIdx.x & 63;
  const int W = blockIdx.x * 4 + w;       // 0..8191
  const int br = W >> 12;
  const int row = W & (NN - 1);
  const float2* __restrict__ U2 = (const float2*)(ws + (br ? US_OFF : UI_OFF));
  float2* __restrict__ O2 = (float2*)(ws + (br ? OS_OFF : OI_OFF));
  const float s1 = ws[S_OFF + (br ? 2*NN : 0) + row];
  const float* __restrict__ s2a = ws + S_OFF + (br ? 3*NN : NN);
  const int cnt = cntbuf[br*NN + row];
  float a0 = 0.f, a1 = 0.f;
  float den = 0.f;

  if (cnt > 0 && cnt <= CAP) {
    const size_t rb = (size_t)(br*NN + row) * CAP;
    int jv[6]; float ev[6];
    float dl = 0.f;
    #pragma unroll
    for (int s = 0; s < 6; ++s) {
      const int p = s*64 + lane;
      if (p < cnt) {
        const int j = (int)idxb[rb + p];
        const float sc = s1 + s2a[j];
        const float e = expf(sc >= 0.f ? sc : SLOPE * sc);
        jv[s] = j; ev[s] = e; dl += e;
      } else { jv[s] = 0; ev[s] = 0.f; }
    }
    #pragma unroll
    for (int off = 32; off; off >>= 1) dl += __shfl_xor(dl, off);
    den = dl;
    #pragma unroll
    for (int s = 0; s < 6; ++s) {
      if (s*64 < cnt) {
        const int qn = min(64, cnt - s*64);
        const int jvs = jv[s]; const float evs = ev[s];
        int q = 0;
        for (; q + 8 <= qn; q += 8) {
          const int j0=__shfl(jvs,q+0), j1=__shfl(jvs,q+1), j2=__shfl(jvs,q+2), j3=__shfl(jvs,q+3);
          const int j4=__shfl(jvs,q+4), j5=__shfl(jvs,q+5), j6=__shfl(jvs,q+6), j7=__shfl(jvs,q+7);
          const float e0=__shfl(evs,q+0), e1=__shfl(evs,q+1), e2=__shfl(evs,q+2), e3=__shfl(evs,q+3);
          const float e4=__shfl(evs,q+4), e5=__shfl(evs,q+5), e6=__shfl(evs,q+6), e7=__shfl(evs,q+7);
          const float2 g0=U2[j0*64+lane], g1=U2[j1*64+lane], g2=U2[j2*64+lane], g3=U2[j3*64+lane];
          const float2 g4=U2[j4*64+lane], g5=U2[j5*64+lane], g6=U2[j6*64+lane], g7=U2[j7*64+lane];
          a0+=e0*g0.x; a1+=e0*g0.y; a0+=e1*g1.x; a1+=e1*g1.y;
          a0+=e2*g2.x; a1+=e2*g2.y; a0+=e3*g3.x; a1+=e3*g3.y;
          a0+=e4*g4.x; a1+=e4*g4.y; a0+=e5*g5.x; a1+=e5*g5.y;
          a0+=e6*g6.x; a1+=e6*g6.y; a0+=e7*g7.x; a1+=e7*g7.y;
        }
        for (; q < qn; ++q) {
          const int j = __shfl(jvs, q); const float e = __shfl(evs, q);
          const float2 g = U2[j*64+lane];
          a0 += e*g.x; a1 += e*g.y;
        }
      }
    }
    float2 o; o.x = a0 / den; o.y = a1 / den;
    O2[row*64 + lane] = o;
  } else if (cnt == 0) {
    // all-masked row -> uniform softmax (never taken at 5% density)
    for (int j = 0; j < NN; ++j) { const float2 g = U2[j*64+lane]; a0 += g.x; a1 += g.y; }
    float2 o; o.x = a0 * (1.f/NN); o.y = a1 * (1.f/NN);
    O2[row*64 + lane] = o;
  } else {
    // list overflow fallback: dense rescan
    const float* __restrict__ Lrow = (br ? Lu : Ld) + (size_t)row * NN;
    for (int j = 0; j < NN; ++j) {
      const float v = Lrow[j];
      if (v != 0.f) {
        const float sc = s1 + s2a[j];
        const float e = expf(sc >= 0.f ? sc : SLOPE * sc);
        const float2 g = U2[j*64+lane];
        a0 += e*g.x; a1 += e*g.y; den += e;
      }
    }
    float2 o; o.x = a0 / den; o.y = a1 / den;
    O2[row*64 + lane] = o;
  }
}

// ---------------------------------------------------------------------------
// z = O_irr + O_sol + sum_k zpart[k] + b_total
__global__ __launch_bounds__(256) void k_combine(const float* __restrict__ ws,
                                                 float* __restrict__ z) {
  const int i = blockIdx.x * 256 + threadIdx.x;
  const int col = i & 127;
  float acc = ws[BT_OFF + col] + ws[OI_OFF + i] + ws[OS_OFF + i];
  #pragma unroll
  for (int kz = 0; kz < 8; ++kz) acc += ws[ZP_OFF + kz*NN*128 + i];
  z[i] = acc;
}

// ---------------------------------------------------------------------------
extern "C" void kernel_launch(void* const* d_in, const int* in_sizes, int n_in,
                              void* d_out, int out_size, void* d_ws, size_t ws_size,
                              hipStream_t stream) {
  const float* x       = (const float*)d_in[0];
  const float* Lu      = (const float*)d_in[1];
  const float* Ld      = (const float*)d_in[2];
  const float* P       = (const float*)d_in[3];
  const float* Wi_w    = (const float*)d_in[4];
  const float* Wi_b    = (const float*)d_in[5];
  const float* Ws_w    = (const float*)d_in[6];
  const float* Ws_b    = (const float*)d_in[7];
  const float* Wh_w    = (const float*)d_in[8];
  const float* Wh_b    = (const float*)d_in[9];
  const float* att_irr = (const float*)d_in[10];
  const float* att_sol = (const float*)d_in[11];
  float* z  = (float*)d_out;
  float* ws = (float*)d_ws;
  unsigned short* idxb = (unsigned short*)((char*)d_ws + IDX_BYTE_OFF);
  float*          valb = (float*)((char*)d_ws + VAL_BYTE_OFF);
  int*            cntb = (int*)((char*)d_ws + CNT_BYTE_OFF);

  k_prep<<<1, 128, 0, stream>>>(Wi_w, Wi_b, Ws_w, Ws_b, Wh_b, att_irr, att_sol, ws);
  k_scores<<<1024, 256, 0, stream>>>(x, ws);
  k_zero<<<32, 256, 0, stream>>>(cntb);
  k_csr<<<8192, 256, 0, stream>>>(Ld, Lu, cntb, idxb, valb);
  k_gather_hx<<<2048, 256, 0, stream>>>(Ld, Lu, x, ws, idxb, valb, cntb);
  {
    dim3 g(128, 3);
    k_ugemm<<<g, 256, 0, stream>>>(x, Wi_w, Ws_w, Wh_w, ws);
  }
  {
    dim3 g(64, 8);
    k_pgemm<<<g, 256, 0, stream>>>(P, ws, ws + ZP_OFF);
  }
  k_attn<<<2048, 256, 0, stream>>>(Ld, Lu, ws, idxb, cntb);
  k_combine<<<NN * 128 / 256, 256, 0, stream>>>(ws, z);
}

// Round 4
// 410.786 us; speedup vs baseline: 1.0121x; 1.0121x over previous
//
#include <hip/hip_runtime.h>

#define NN 4096
#define CAP 384          // nnz/row: mean 205, sd 13.9 -> 384 is +12.9 sd; dense fallback guards
#define SLOPE 0.2f

typedef __attribute__((ext_vector_type(8))) short bf16x8;
typedef __attribute__((ext_vector_type(4))) float f32x4;

static __device__ __forceinline__ short f2bf(float f) {   // RNE fp32->bf16
  unsigned u = __builtin_bit_cast(unsigned, f);
  unsigned r = (u + 0x7fffu + ((u >> 16) & 1u)) >> 16;
  return (short)r;
}

// ---- workspace layout (float offsets unless noted) ----
#define V_OFF     0                        // v1i,v2i,v1s,v2s : 4*128
#define C_OFF     512                      // 4 score constants
#define BT_OFF    516                      // b_total[128]
#define S_OFF     1024                     // s1i,s2i,s1s,s2s : 4*4096
#define HXI_OFF   32768                    // Ld@x   [4096,128]
#define HXS_OFF   (HXI_OFF + NN*128)       // Lu@x
#define UI_OFF    (HXS_OFF + NN*128)       // x@Wi0 + Hxi@Wi1
#define US_OFF    (UI_OFF + NN*128)        // x@Ws0 + Hxs@Ws1
#define XWH_OFF   (US_OFF + NN*128)        // x@Wh (fp32)
#define OI_OFF    (XWH_OFF + NN*128)       // alpha_irr @ U_irr
#define OS_OFF    (OI_OFF + NN*128)        // alpha_sol @ U_sol
#define ZP_OFF    (OS_OFF + NN*128)        // P@xWh split-K partials: 8 * [4096,128]
#define WS_FLOATS (ZP_OFF + 8*NN*128)
#define IDX_BYTE_OFF ((size_t)WS_FLOATS * 4)                  // u16 idx lists 2*4096*CAP
#define VAL_BYTE_OFF (IDX_BYTE_OFF + (size_t)2*NN*CAP*2)      // f32 val lists
#define CNT_BYTE_OFF (VAL_BYTE_OFF + (size_t)2*NN*CAP*4)      // int counts 2*4096
#define XWT_BYTE_OFF (CNT_BYTE_OFF + (size_t)2*NN*4)          // bf16 XwT [128][4096]
// total ws ≈ 51.5 MiB

// ---------------------------------------------------------------------------
// Prep: v-vectors so s1[i] = x[i,:]·v + c (x_irr never materialized), b_total.
__global__ __launch_bounds__(128) void k_prep(
    const float* __restrict__ Wi_w, const float* __restrict__ Wi_b,
    const float* __restrict__ Ws_w, const float* __restrict__ Ws_b,
    const float* __restrict__ Wh_b, const float* __restrict__ att_irr,
    const float* __restrict__ att_sol, float* __restrict__ ws) {
  const int t = threadIdx.x;  // one thread per input channel c
  float v1i = 0.f, v2i = 0.f, v1s = 0.f, v2s = 0.f;
  for (int j = 0; j < 2; ++j) {
    for (int o = 0; o < 128; ++o) {
      const float wi = Wi_w[j*16384 + t*128 + o];
      const float wv = Ws_w[j*16384 + t*128 + o];
      v1i += wi * att_irr[j*128 + o];
      v2i += wi * att_irr[256 + j*128 + o];
      v1s += wv * att_sol[j*128 + o];
      v2s += wv * att_sol[256 + j*128 + o];
    }
  }
  ws[V_OFF + t]       = v1i;
  ws[V_OFF + 128 + t] = v2i;
  ws[V_OFF + 256 + t] = v1s;
  ws[V_OFF + 384 + t] = v2s;
  ws[BT_OFF + t] = Wi_b[t] + Wi_b[128 + t] + Ws_b[t] + Ws_b[128 + t] + Wh_b[t];
  if (t < 4) {
    const float* bb = (t < 2) ? Wi_b : Ws_b;
    const float* aa = ((t < 2) ? att_irr : att_sol) + ((t & 1) ? 256 : 0);
    float c = 0.f;
    for (int k = 0; k < 256; ++k) c += bb[k] * aa[k];
    ws[C_OFF + t] = c;   // c1i, c2i, c1s, c2s
  }
}

// ---------------------------------------------------------------------------
__global__ __launch_bounds__(256) void k_scores(const float* __restrict__ x,
                                                float* __restrict__ ws) {
  const int wave = threadIdx.x >> 6, lane = threadIdx.x & 63;
  const int row = blockIdx.x * 4 + wave;
  const float* v = ws + V_OFF;
  const float x0 = x[row*128 + lane];
  const float x1 = x[row*128 + 64 + lane];
  float p0 = x0 * v[lane]       + x1 * v[64 + lane];
  float p1 = x0 * v[128 + lane] + x1 * v[192 + lane];
  float p2 = x0 * v[256 + lane] + x1 * v[320 + lane];
  float p3 = x0 * v[384 + lane] + x1 * v[448 + lane];
  #pragma unroll
  for (int off = 32; off; off >>= 1) {
    p0 += __shfl_down(p0, off);
    p1 += __shfl_down(p1, off);
    p2 += __shfl_down(p2, off);
    p3 += __shfl_down(p3, off);
  }
  if (lane == 0) {
    ws[S_OFF + row]          = p0 + ws[C_OFF + 0];  // s1_irr
    ws[S_OFF + NN + row]     = p1 + ws[C_OFF + 1];  // s2_irr
    ws[S_OFF + 2*NN + row]   = p2 + ws[C_OFF + 2];  // s1_sol
    ws[S_OFF + 3*NN + row]   = p3 + ws[C_OFF + 3];  // s2_sol
  }
}

// ---------------------------------------------------------------------------
__global__ __launch_bounds__(256) void k_zero(int* __restrict__ cnt) {
  cnt[blockIdx.x * 256 + threadIdx.x] = 0;   // grid 32 -> 8192 counters
}

// ---------------------------------------------------------------------------
// CSR build: one wave per quarter-row (1024 elements). 16 independent ballots,
// ONE global atomic per wave, scatter-store (idx u16, val f32).
__global__ __launch_bounds__(256) void k_csr(
    const float* __restrict__ Ld, const float* __restrict__ Lu,
    int* __restrict__ cntbuf, unsigned short* __restrict__ idxb,
    float* __restrict__ valb) {
  const int w = threadIdx.x >> 6, lane = threadIdx.x & 63;
  const int W = blockIdx.x * 4 + w;          // 0..32767
  const int br = W >> 14;                    // 16384 quarter-chunks per matrix
  const int row = (W >> 2) & (NN - 1);
  const int quarter = W & 3;
  const float4* __restrict__ L4 =
      (const float4*)((br ? Lu : Ld) + (size_t)row * NN + quarter * 1024);
  float4 lv[4];
  #pragma unroll
  for (int i = 0; i < 4; ++i) lv[i] = L4[i*64 + lane];

  unsigned long long m[16];
  int runs[16];
  int run = 0;
  #pragma unroll
  for (int i = 0; i < 4; ++i)
    #pragma unroll
    for (int c = 0; c < 4; ++c) {
      const int r = i*4 + c;
      m[r] = __ballot((&lv[i].x)[c] != 0.f);
      runs[r] = run;
      run += (int)__popcll(m[r]);
    }
  int base = 0;
  if (lane == 0 && run) base = atomicAdd(&cntbuf[br*NN + row], run);
  base = __shfl(base, 0);
  const size_t rb = (size_t)(br*NN + row) * CAP;
  const unsigned long long lmask = (1ull << lane) - 1ull;
  #pragma unroll
  for (int i = 0; i < 4; ++i)
    #pragma unroll
    for (int c = 0; c < 4; ++c) {
      const int r = i*4 + c;
      const float v = (&lv[i].x)[c];
      if (v != 0.f) {
        const int pos = base + runs[r] + (int)__popcll(m[r] & lmask);
        if (pos < CAP) {
          idxb[rb + pos] = (unsigned short)(quarter*1024 + (i*64 + lane)*4 + c);
          valb[rb + pos] = v;
        }
      }
    }
}

// ---------------------------------------------------------------------------
// Hx = L@x per row. One wave per row, no LDS, no barriers.
__global__ __launch_bounds__(256) void k_gather_hx(
    const float* __restrict__ Ld, const float* __restrict__ Lu,
    const float* __restrict__ x, float* __restrict__ ws,
    const unsigned short* __restrict__ idxb, const float* __restrict__ valb,
    const int* __restrict__ cntbuf) {
  const int w = threadIdx.x >> 6, lane = threadIdx.x & 63;
  const int W = blockIdx.x * 4 + w;       // 0..8191
  const int br = W >> 12;
  const int row = W & (NN - 1);
  const float2* __restrict__ x2 = (const float2*)x;
  float2* __restrict__ Hx2 = (float2*)(ws + (br ? HXS_OFF : HXI_OFF));
  const int cnt = cntbuf[br*NN + row];
  float a0 = 0.f, a1 = 0.f;
  if (cnt <= CAP) {
    const size_t rb = (size_t)(br*NN + row) * CAP;
    int jv[6]; float vv[6];
    #pragma unroll
    for (int s = 0; s < 6; ++s) {
      const int p = s*64 + lane;
      const bool in = p < cnt;
      jv[s] = in ? (int)idxb[rb + p] : 0;
      vv[s] = in ? valb[rb + p] : 0.f;
    }
    #pragma unroll
    for (int s = 0; s < 6; ++s) {
      if (s*64 < cnt) {
        const int qn = min(64, cnt - s*64);
        const int jvs = jv[s]; const float vvs = vv[s];
        int q = 0;
        for (; q + 8 <= qn; q += 8) {
          const int j0=__shfl(jvs,q+0), j1=__shfl(jvs,q+1), j2=__shfl(jvs,q+2), j3=__shfl(jvs,q+3);
          const int j4=__shfl(jvs,q+4), j5=__shfl(jvs,q+5), j6=__shfl(jvs,q+6), j7=__shfl(jvs,q+7);
          const float v0=__shfl(vvs,q+0), v1=__shfl(vvs,q+1), v2=__shfl(vvs,q+2), v3=__shfl(vvs,q+3);
          const float v4=__shfl(vvs,q+4), v5=__shfl(vvs,q+5), v6=__shfl(vvs,q+6), v7=__shfl(vvs,q+7);
          const float2 g0=x2[j0*64+lane], g1=x2[j1*64+lane], g2=x2[j2*64+lane], g3=x2[j3*64+lane];
          const float2 g4=x2[j4*64+lane], g5=x2[j5*64+lane], g6=x2[j6*64+lane], g7=x2[j7*64+lane];
          a0+=v0*g0.x; a1+=v0*g0.y; a0+=v1*g1.x; a1+=v1*g1.y;
          a0+=v2*g2.x; a1+=v2*g2.y; a0+=v3*g3.x; a1+=v3*g3.y;
          a0+=v4*g4.x; a1+=v4*g4.y; a0+=v5*g5.x; a1+=v5*g5.y;
          a0+=v6*g6.x; a1+=v6*g6.y; a0+=v7*g7.x; a1+=v7*g7.y;
        }
        for (; q < qn; ++q) {
          const int j = __shfl(jvs, q); const float v = __shfl(vvs, q);
          const float2 g = x2[j*64+lane];
          a0 += v*g.x; a1 += v*g.y;
        }
      }
    }
  } else {   // overflow fallback: dense rescan (never taken at 5% density)
    const float* __restrict__ Lrow = (br ? Lu : Ld) + (size_t)row * NN;
    for (int j = 0; j < NN; ++j) {
      const float v = Lrow[j];
      if (v != 0.f) { const float2 g = x2[j*64+lane]; a0 += v*g.x; a1 += v*g.y; }
    }
  }
  float2 o; o.x = a0; o.y = a1;
  Hx2[row*64 + lane] = o;
}

// ---------------------------------------------------------------------------
// Small GEMMs: U_irr = x@Wi0 + Hxi@Wi1 ; U_sol = x@Ws0 + Hxs@Ws1 ; xWh = x@Wh.
__global__ __launch_bounds__(256) void k_ugemm(
    const float* __restrict__ x, const float* __restrict__ Wi_w,
    const float* __restrict__ Ws_w, const float* __restrict__ Wh_w,
    float* __restrict__ ws) {
  const int rb = blockIdx.x;       // 128 row-blocks of 32
  const int sel = blockIdx.y;      // 0:U_irr 1:U_sol 2:xWh
  const float* A[2]; const float* W[2]; int npass; float* out;
  if (sel == 0)      { A[0]=x; W[0]=Wi_w; A[1]=ws+HXI_OFF; W[1]=Wi_w+16384; npass=2; out=ws+UI_OFF; }
  else if (sel == 1) { A[0]=x; W[0]=Ws_w; A[1]=ws+HXS_OFF; W[1]=Ws_w+16384; npass=2; out=ws+US_OFF; }
  else               { A[0]=x; W[0]=Wh_w; A[1]=nullptr;    W[1]=nullptr;    npass=1; out=ws+XWH_OFF; }

  __shared__ __align__(16) float At[32][33];
  __shared__ __align__(16) float Wt[32][132];
  const int t = threadIdx.x;
  const int rg = t >> 4, cg = t & 15;
  const int r0 = rb * 32;
  float acc[2][8];
  #pragma unroll
  for (int i = 0; i < 2; ++i)
    #pragma unroll
    for (int j = 0; j < 8; ++j) acc[i][j] = 0.f;

  for (int ps = 0; ps < npass; ++ps) {
    const float* __restrict__ Ap = A[ps];
    const float* __restrict__ Wp = W[ps];
    for (int k0 = 0; k0 < 128; k0 += 32) {
      __syncthreads();
      { const int row = t >> 3, kq = t & 7;
        const float4 av = *(const float4*)&Ap[(r0 + row)*128 + k0 + kq*4];
        At[row][kq*4+0] = av.x; At[row][kq*4+1] = av.y;
        At[row][kq*4+2] = av.z; At[row][kq*4+3] = av.w; }
      #pragma unroll
      for (int l = 0; l < 4; ++l) {
        const int idx = t + l*256;
        const int kr = idx >> 5, c4 = idx & 31;
        const float4 wv = *(const float4*)&Wp[(k0 + kr)*128 + c4*4];
        Wt[kr][c4*4+0] = wv.x; Wt[kr][c4*4+1] = wv.y;
        Wt[kr][c4*4+2] = wv.z; Wt[kr][c4*4+3] = wv.w;
      }
      __syncthreads();
      #pragma unroll
      for (int k = 0; k < 32; ++k) {
        const float a0 = At[rg*2 + 0][k];
        const float a1 = At[rg*2 + 1][k];
        const float4 b0 = *(const float4*)&Wt[k][cg*8];
        const float4 b1 = *(const float4*)&Wt[k][cg*8 + 4];
        acc[0][0] += a0*b0.x; acc[0][1] += a0*b0.y; acc[0][2] += a0*b0.z; acc[0][3] += a0*b0.w;
        acc[0][4] += a0*b1.x; acc[0][5] += a0*b1.y; acc[0][6] += a0*b1.z; acc[0][7] += a0*b1.w;
        acc[1][0] += a1*b0.x; acc[1][1] += a1*b0.y; acc[1][2] += a1*b0.z; acc[1][3] += a1*b0.w;
        acc[1][4] += a1*b1.x; acc[1][5] += a1*b1.y; acc[1][6] += a1*b1.z; acc[1][7] += a1*b1.w;
      }
    }
  }
  #pragma unroll
  for (int i = 0; i < 2; ++i) {
    const int r = r0 + rg*2 + i;
    #pragma unroll
    for (int j = 0; j < 8; ++j) out[r*128 + cg*8 + j] = acc[i][j];
  }
}

// ---------------------------------------------------------------------------
// Transpose xWh (fp32 [4096k][128n]) -> XwT (bf16 [128n][4096k]) for MFMA B.
__global__ __launch_bounds__(256) void k_xwt(const float* __restrict__ ws,
                                             unsigned short* __restrict__ XwT) {
  const float* __restrict__ Xw = ws + XWH_OFF;
  __shared__ float tile[64][133];
  const int t = threadIdx.x;
  const int k0 = blockIdx.x * 64;
  #pragma unroll
  for (int lp = 0; lp < 8; ++lp) {
    const int idx = t + lp*256;           // 2048 float4s = 64x128 floats
    const int r = idx >> 5, c4 = idx & 31;
    const float4 v = *(const float4*)&Xw[(size_t)(k0 + r)*128 + c4*4];
    tile[r][c4*4+0]=v.x; tile[r][c4*4+1]=v.y; tile[r][c4*4+2]=v.z; tile[r][c4*4+3]=v.w;
  }
  __syncthreads();
  const int n = t >> 1, seg = t & 1;
  unsigned out[16];
  #pragma unroll
  for (int q = 0; q < 16; ++q) {
    const int kk = seg*32 + q*2;
    const unsigned lo = (unsigned)(unsigned short)f2bf(tile[kk][n]);
    const unsigned hi = (unsigned)(unsigned short)f2bf(tile[kk+1][n]);
    out[q] = lo | (hi << 16);
  }
  unsigned* __restrict__ dst = (unsigned*)&XwT[(size_t)n*NN + k0 + seg*32];
  #pragma unroll
  for (int q = 0; q < 16; ++q) dst[q] = out[q];
}

// ---------------------------------------------------------------------------
// Dense P @ xWh on the MATRIX CORES. No LDS. Each wave: 16 rows x 128 cols.
// A-frag: P fp32 loaded coalesced (wave = 16 rows x 128B), converted bf16
// in-register. B-frag: 16B contiguous loads from L2-resident XwT.
// Split-K=8 (grid.y), deterministic partial buffers.
__global__ __launch_bounds__(256) void k_pgemm(const float* __restrict__ P,
                                               const unsigned short* __restrict__ XwT,
                                               float* __restrict__ zpart) {
  const int t = threadIdx.x;
  const int w = t >> 6, l = t & 63;
  const int quad = l >> 4, m16 = l & 15;
  const int r0 = blockIdx.x * 64;         // 64 rows/block (4 waves x 16)
  const int kz = blockIdx.y;              // 8 K-splits of 512
  const int row = r0 + w*16 + m16;
  const float* __restrict__ Arow = P + (size_t)row * NN;
  const int kbase = kz * 512;

  f32x4 acc[8];
  #pragma unroll
  for (int nt = 0; nt < 8; ++nt) acc[nt] = (f32x4){0.f, 0.f, 0.f, 0.f};

  float4 a0 = *(const float4*)&Arow[kbase + quad*8];
  float4 a1 = *(const float4*)&Arow[kbase + quad*8 + 4];
  for (int ks = 0; ks < 16; ++ks) {
    const int k0 = kbase + ks*32;
    bf16x8 bf[8];
    #pragma unroll
    for (int nt = 0; nt < 8; ++nt)
      bf[nt] = *(const bf16x8*)&XwT[(size_t)(nt*16 + m16) * NN + k0 + quad*8];
    float4 na0, na1;
    if (ks < 15) {               // software prefetch next A while MFMAs run
      na0 = *(const float4*)&Arow[k0 + 32 + quad*8];
      na1 = *(const float4*)&Arow[k0 + 32 + quad*8 + 4];
    }
    bf16x8 af;
    af[0]=f2bf(a0.x); af[1]=f2bf(a0.y); af[2]=f2bf(a0.z); af[3]=f2bf(a0.w);
    af[4]=f2bf(a1.x); af[5]=f2bf(a1.y); af[6]=f2bf(a1.z); af[7]=f2bf(a1.w);
    #pragma unroll
    for (int nt = 0; nt < 8; ++nt)
      acc[nt] = __builtin_amdgcn_mfma_f32_16x16x32_bf16(af, bf[nt], acc[nt], 0, 0, 0);
    a0 = na0; a1 = na1;
  }
  float* __restrict__ zp = zpart + (size_t)kz * NN * 128;
  // C/D layout: col = lane&15, row = quad*4 + reg  [verified m89/m91]
  #pragma unroll
  for (int nt = 0; nt < 8; ++nt)
    #pragma unroll
    for (int r = 0; r < 4; ++r)
      zp[(size_t)(r0 + w*16 + quad*4 + r)*128 + nt*16 + m16] = acc[nt][r];
}

// ---------------------------------------------------------------------------
// Attention: one wave per (row,branch), no LDS/barriers. Pass 1: e_j into regs
// + wave-reduced denominator. Pass 2: shfl-broadcast, 8 U-gathers in flight.
__global__ __launch_bounds__(256) void k_attn(
    const float* __restrict__ Ld, const float* __restrict__ Lu,
    float* __restrict__ ws, const unsigned short* __restrict__ idxb,
    const int* __restrict__ cntbuf) {
  const int w = threadIdx.x >> 6, lane = threadIdx.x & 63;
  const int W = blockIdx.x * 4 + w;       // 0..8191
  const int br = W >> 12;
  const int row = W & (NN - 1);
  const float2* __restrict__ U2 = (const float2*)(ws + (br ? US_OFF : UI_OFF));
  float2* __restrict__ O2 = (float2*)(ws + (br ? OS_OFF : OI_OFF));
  const float s1 = ws[S_OFF + (br ? 2*NN : 0) + row];
  const float* __restrict__ s2a = ws + S_OFF + (br ? 3*NN : NN);
  const int cnt = cntbuf[br*NN + row];
  float a0 = 0.f, a1 = 0.f;
  float den = 0.f;

  if (cnt > 0 && cnt <= CAP) {
    const size_t rb = (size_t)(br*NN + row) * CAP;
    int jv[6]; float ev[6];
    float dl = 0.f;
    #pragma unroll
    for (int s = 0; s < 6; ++s) {
      const int p = s*64 + lane;
      if (p < cnt) {
        const int j = (int)idxb[rb + p];
        const float sc = s1 + s2a[j];
        const float e = expf(sc >= 0.f ? sc : SLOPE * sc);
        jv[s] = j; ev[s] = e; dl += e;
      } else { jv[s] = 0; ev[s] = 0.f; }
    }
    #pragma unroll
    for (int off = 32; off; off >>= 1) dl += __shfl_xor(dl, off);
    den = dl;
    #pragma unroll
    for (int s = 0; s < 6; ++s) {
      if (s*64 < cnt) {
        const int qn = min(64, cnt - s*64);
        const int jvs = jv[s]; const float evs = ev[s];
        int q = 0;
        for (; q + 8 <= qn; q += 8) {
          const int j0=__shfl(jvs,q+0), j1=__shfl(jvs,q+1), j2=__shfl(jvs,q+2), j3=__shfl(jvs,q+3);
          const int j4=__shfl(jvs,q+4), j5=__shfl(jvs,q+5), j6=__shfl(jvs,q+6), j7=__shfl(jvs,q+7);
          const float e0=__shfl(evs,q+0), e1=__shfl(evs,q+1), e2=__shfl(evs,q+2), e3=__shfl(evs,q+3);
          const float e4=__shfl(evs,q+4), e5=__shfl(evs,q+5), e6=__shfl(evs,q+6), e7=__shfl(evs,q+7);
          const float2 g0=U2[j0*64+lane], g1=U2[j1*64+lane], g2=U2[j2*64+lane], g3=U2[j3*64+lane];
          const float2 g4=U2[j4*64+lane], g5=U2[j5*64+lane], g6=U2[j6*64+lane], g7=U2[j7*64+lane];
          a0+=e0*g0.x; a1+=e0*g0.y; a0+=e1*g1.x; a1+=e1*g1.y;
          a0+=e2*g2.x; a1+=e2*g2.y; a0+=e3*g3.x; a1+=e3*g3.y;
          a0+=e4*g4.x; a1+=e4*g4.y; a0+=e5*g5.x; a1+=e5*g5.y;
          a0+=e6*g6.x; a1+=e6*g6.y; a0+=e7*g7.x; a1+=e7*g7.y;
        }
        for (; q < qn; ++q) {
          const int j = __shfl(jvs, q); const float e = __shfl(evs, q);
          const float2 g = U2[j*64+lane];
          a0 += e*g.x; a1 += e*g.y;
        }
      }
    }
    float2 o; o.x = a0 / den; o.y = a1 / den;
    O2[row*64 + lane] = o;
  } else if (cnt == 0) {
    for (int j = 0; j < NN; ++j) { const float2 g = U2[j*64+lane]; a0 += g.x; a1 += g.y; }
    float2 o; o.x = a0 * (1.f/NN); o.y = a1 * (1.f/NN);
    O2[row*64 + lane] = o;
  } else {
    const float* __restrict__ Lrow = (br ? Lu : Ld) + (size_t)row * NN;
    for (int j = 0; j < NN; ++j) {
      const float v = Lrow[j];
      if (v != 0.f) {
        const float sc = s1 + s2a[j];
        const float e = expf(sc >= 0.f ? sc : SLOPE * sc);
        const float2 g = U2[j*64+lane];
        a0 += e*g.x; a1 += e*g.y; den += e;
      }
    }
    float2 o; o.x = a0 / den; o.y = a1 / den;
    O2[row*64 + lane] = o;
  }
}

// ---------------------------------------------------------------------------
// z = O_irr + O_sol + sum_k zpart[k] + b_total
__global__ __launch_bounds__(256) void k_combine(const float* __restrict__ ws,
                                                 float* __restrict__ z) {
  const int i = blockIdx.x * 256 + threadIdx.x;
  const int col = i & 127;
  float acc = ws[BT_OFF + col] + ws[OI_OFF + i] + ws[OS_OFF + i];
  #pragma unroll
  for (int kz = 0; kz < 8; ++kz) acc += ws[ZP_OFF + kz*NN*128 + i];
  z[i] = acc;
}

// ---------------------------------------------------------------------------
extern "C" void kernel_launch(void* const* d_in, const int* in_sizes, int n_in,
                              void* d_out, int out_size, void* d_ws, size_t ws_size,
                              hipStream_t stream) {
  const float* x       = (const float*)d_in[0];
  const float* Lu      = (const float*)d_in[1];
  const float* Ld      = (const float*)d_in[2];
  const float* P       = (const float*)d_in[3];
  const float* Wi_w    = (const float*)d_in[4];
  const float* Wi_b    = (const float*)d_in[5];
  const float* Ws_w    = (const float*)d_in[6];
  const float* Ws_b    = (const float*)d_in[7];
  const float* Wh_w    = (const float*)d_in[8];
  const float* Wh_b    = (const float*)d_in[9];
  const float* att_irr = (const float*)d_in[10];
  const float* att_sol = (const float*)d_in[11];
  float* z  = (float*)d_out;
  float* ws = (float*)d_ws;
  unsigned short* idxb = (unsigned short*)((char*)d_ws + IDX_BYTE_OFF);
  float*          valb = (float*)((char*)d_ws + VAL_BYTE_OFF);
  int*            cntb = (int*)((char*)d_ws + CNT_BYTE_OFF);
  unsigned short* xwtb = (unsigned short*)((char*)d_ws + XWT_BYTE_OFF);

  k_prep<<<1, 128, 0, stream>>>(Wi_w, Wi_b, Ws_w, Ws_b, Wh_b, att_irr, att_sol, ws);
  k_scores<<<1024, 256, 0, stream>>>(x, ws);
  k_zero<<<32, 256, 0, stream>>>(cntb);
  k_csr<<<8192, 256, 0, stream>>>(Ld, Lu, cntb, idxb, valb);
  k_gather_hx<<<2048, 256, 0, stream>>>(Ld, Lu, x, ws, idxb, valb, cntb);
  {
    dim3 g(128, 3);
    k_ugemm<<<g, 256, 0, stream>>>(x, Wi_w, Ws_w, Wh_w, ws);
  }
  k_xwt<<<64, 256, 0, stream>>>(ws, xwtb);
  {
    dim3 g(64, 8);
    k_pgemm<<<g, 256, 0, stream>>>(P, xwtb, ws + ZP_OFF);
  }
  k_attn<<<2048, 256, 0, stream>>>(Ld, Lu, ws, idxb, cntb);
  k_combine<<<NN * 128 / 256, 256, 0, stream>>>(ws, z);
}